// Round 6
// baseline (108.269 us; speedup 1.0000x reference)
//
#include <hip/hip_runtime.h>

typedef __bf16 bf16x8 __attribute__((ext_vector_type(8)));
typedef float f32x4 __attribute__((ext_vector_type(4)));
typedef unsigned short ushort8 __attribute__((ext_vector_type(8)));
typedef unsigned short ushort4v __attribute__((ext_vector_type(4)));

#define S_LEN 2048
#define DMODEL 1024
#define DHEAD 64
#define QK_SCALE 0.18033688f  /* (1/8) * log2(e) */

static __device__ __forceinline__ unsigned short f2bf(float x) {
  __bf16 h = (__bf16)x;
  return __builtin_bit_cast(unsigned short, h);
}

static __device__ __forceinline__ f32x4 mfma16(bf16x8 a, bf16x8 b, f32x4 c) {
  return __builtin_amdgcn_mfma_f32_16x16x32_bf16(a, b, c, 0, 0, 0);
}

// ---- fused prep: wiT [64][1024] bf16  +  wosumT [1024][64] bf16
// wosumT[j][d] = sum_h Wo[h*64+d][j]  (tile(head,16)@Wo == head@Wo_sum; B-frag layout)
__global__ void prep_kernel(const float* __restrict__ wi, const float* __restrict__ Wo,
                            unsigned short* __restrict__ wiT,
                            unsigned short* __restrict__ wosumT) {
  int i = blockIdx.x * 256 + threadIdx.x;  // 131072 total
  if (i < 65536) {
    int n = i >> 10, kk = i & 1023;
    wiT[i] = f2bf(wi[(size_t)kk * DHEAD + n]);
  } else {
    int idx = i - 65536;
    int j = idx & 1023, d = idx >> 10;  // consecutive lanes -> consecutive j (coalesced)
    float s = 0.f;
#pragma unroll
    for (int h = 0; h < 16; ++h) s += Wo[(size_t)(h * 64 + d) * 1024 + j];
    wosumT[(size_t)j * 64 + d] = f2bf(s);
  }
}

// ---- cvt: the ONLY kernel that reads the 96MB fp32 inputs. m13-shaped streaming:
// zero LDS, low VGPR, 3072x256, 8 independent 16B reads/thread (dense per-slice
// fronts), fp32->bf16, write xbf [3][8192][1024] bf16 (48MB).
// r0-r5 post-mortem: every proj variant coupled the HBM read to GEMM structure,
// capping outstanding reads (<=20 waves/CU, <=2 loads in flight/wave after the RA
// got done with it) -> 1.3 TB/s invariant. The guide's m13 float4-copy (6.3 TB/s)
// is THIS shape. If cvt too runs at 1.3, the environment read-cap is proven.
__global__ __launch_bounds__(256) void cvt_kernel(
    const float* __restrict__ q, const float* __restrict__ k, const float* __restrict__ v,
    unsigned short* __restrict__ xbf) {
  int bx = blockIdx.x;
  int ten = bx >> 10;  // 1024 blocks per tensor
  const float* x = (ten == 0) ? q : ((ten == 1) ? k : v);
  int idx = ((bx & 1023) << 8) + threadIdx.x;  // chunk id within tensor (f32x4 units)
  const f32x4* src = (const f32x4*)x + idx;
  unsigned short* dst = xbf + (size_t)ten * 8388608;

  f32x4 c0 = src[0 * 262144];
  f32x4 c1 = src[1 * 262144];
  f32x4 c2 = src[2 * 262144];
  f32x4 c3 = src[3 * 262144];
  f32x4 c4 = src[4 * 262144];
  f32x4 c5 = src[5 * 262144];
  f32x4 c6 = src[6 * 262144];
  f32x4 c7 = src[7 * 262144];

#define CVT_ST(J, C)                                                   \
  {                                                                    \
    ushort4v h;                                                        \
    h[0] = f2bf(C[0]); h[1] = f2bf(C[1]);                              \
    h[2] = f2bf(C[2]); h[3] = f2bf(C[3]);                              \
    *(ushort4v*)(dst + ((size_t)idx + J * 262144) * 4) = h;            \
  }
  CVT_ST(0, c0) CVT_ST(1, c1) CVT_ST(2, c2) CVT_ST(3, c3)
  CVT_ST(4, c4) CVT_ST(5, c5) CVT_ST(6, c6) CVT_ST(7, c7)
#undef CVT_ST
}

// ---- projections v6: GEMM from L3-resident bf16.
// Phase A: stage the 32KB contiguous bf16 tile (16 rows x 2048B) into swizzled LDS --
// 8 independent 16B loads/thread from L3 (latency ~half HBM, half the bytes of fp32).
// Phase B: wave w owns cols w*16..+16; one ds_read_b128 per MFMA, B streamed from
// L2-resident wiT. Epilogue unchanged (verified D-layout).
__global__ __launch_bounds__(256, 4) void proj_kernel(
    const unsigned short* __restrict__ xbf, const unsigned short* __restrict__ wiT,
    float* __restrict__ qp32, unsigned short* __restrict__ qp_bf,
    unsigned short* __restrict__ kp_bf, unsigned short* __restrict__ vpT) {
  int bx = blockIdx.x;       // 1536 blocks: 512 per tensor
  int ten = bx >> 9;         // 0:q 1:k 2:v
  int m0 = (bx & 511) << 4;  // 16-row strip
  int tid = threadIdx.x, lane = tid & 63, w = tid >> 6;
  int l15 = lane & 15, lg = lane >> 4;

  __shared__ __align__(16) unsigned short Abf[16][1024];  // 32KB, row-XOR-swizzled

  // ---- Phase A: contiguous 32KB scan -> swizzled LDS
  const char* src = (const char*)(xbf + (size_t)ten * 8388608 + (size_t)m0 * 1024) + tid * 16;
  ushort8 ld0 = *(const ushort8*)(src + 0 * 4096);
  ushort8 ld1 = *(const ushort8*)(src + 1 * 4096);
  ushort8 ld2 = *(const ushort8*)(src + 2 * 4096);
  ushort8 ld3 = *(const ushort8*)(src + 3 * 4096);
  ushort8 ld4 = *(const ushort8*)(src + 4 * 4096);
  ushort8 ld5 = *(const ushort8*)(src + 5 * 4096);
  ushort8 ld6 = *(const ushort8*)(src + 6 * 4096);
  ushort8 ld7 = *(const ushort8*)(src + 7 * 4096);
  int colb = (tid & 127) * 16;
#define STG(S, LD)                                                               \
  {                                                                              \
    int row = S * 2 + (tid >> 7);                                                \
    *(ushort8*)((char*)&Abf[0][0] + row * 2048 + (colb ^ ((row & 7) << 4))) = LD; \
  }
  STG(0, ld0) STG(1, ld1) STG(2, ld2) STG(3, ld3)
  STG(4, ld4) STG(5, ld5) STG(6, ld6) STG(7, ld7)
#undef STG
  __syncthreads();

  // ---- Phase B: out[m=0..15][n=w*16..+16] over K=1024
  f32x4 acc = {};
  const char* Arow = (const char*)&Abf[l15][0];  // m = l15
  const unsigned short* bcol = wiT + (size_t)(w * 16 + l15) * 1024 + lg * 8;  // n = w*16+l15
  int swz = (l15 & 7) << 4;
#pragma unroll
  for (int s = 0; s < 32; ++s) {
    bf16x8 af = *(const bf16x8*)(Arow + ((s * 64 + lg * 16) ^ swz));
    bf16x8 bfr = *(const bf16x8*)(bcol + s * 32);
    acc = mfma16(af, bfr, acc);
  }

  // ---- epilogue: C row = m0 + lg*4 + r, col = w*16 + l15 (verified D-layout)
  if (ten == 2) {
    __syncthreads();  // all waves done reading Abf before reuse
    unsigned short(*vt)[68] = (unsigned short(*)[68]) & Abf[0][0];  // [kv 16][d 64+pad]
#pragma unroll
    for (int r = 0; r < 4; ++r) vt[lg * 4 + r][w * 16 + l15] = f2bf(acc[r]);
    __syncthreads();
    int d = tid >> 2, c4 = (tid & 3) << 2;
    ushort4v o;
#pragma unroll
    for (int j = 0; j < 4; ++j) o[j] = vt[c4 + j][d];
    int bq = m0 >> 11, kvb = m0 & 2047;
    *(ushort4v*)(vpT + (size_t)bq * (DHEAD * S_LEN) + (size_t)d * S_LEN + kvb + c4) = o;
  } else {
#pragma unroll
    for (int r = 0; r < 4; ++r) {
      size_t idx = (size_t)(m0 + lg * 4 + r) * DHEAD + (w * 16 + l15);
      float val = acc[r];
      if (ten == 0) {
        qp32[idx] = val;
        qp_bf[idx] = f2bf(val * QK_SCALE);
      } else {
        kp_bf[idx] = f2bf(val);
      }
    }
  }
}

// ---- flash attention, fixed-max softmax, 4-way KV split per block
// NO in-loop barriers: P_lds[w] is written AND read by wave w only -- the
// compiler's lgkmcnt dependency wait orders the round-trip. Waves fully
// decoupled until the final cross-wave combine barrier.
__global__ __launch_bounds__(256) void attn_kernel(
    const unsigned short* __restrict__ qp_bf, const unsigned short* __restrict__ kp_bf,
    const unsigned short* __restrict__ vpT, const float* __restrict__ qp32,
    unsigned short* __restrict__ head_bf) {
  int bx = blockIdx.x;
  int b = bx >> 7;
  int q0 = (bx & 127) << 4;
  int tid = threadIdx.x, lane = tid & 63, w = tid >> 6;
  int l15 = lane & 15, lg = lane >> 4;

  __shared__ __align__(16) unsigned short P_lds[4][16][72];  // per-wave P round-trip
  __shared__ __align__(16) float part[4][16][64];            // per-wave PV partials
  __shared__ float lsum_lds[4][16];                          // per-wave denom partials

  size_t base = (size_t)b * (S_LEN * DHEAD);
  const unsigned short* qrow_p = qp_bf + base + (size_t)(q0 + l15) * DHEAD + lg * 8;
  bf16x8 qf0 = *(const bf16x8*)qrow_p;  // B-frag: n=q, k=dh
  bf16x8 qf1 = *(const bf16x8*)(qrow_p + 32);

  const unsigned short* vbase = vpT + (size_t)b * (DHEAD * S_LEN);

  f32x4 oacc[4] = {};
  float lsum_p = 0.f;  // per-lane partial denom for q = q0 + l15

  for (int it = 0; it < 8; ++it) {
    int kv0 = w * 512 + it * 64;
    const unsigned short* kt = kp_bf + base + (size_t)kv0 * DHEAD;
    f32x4 sc[4];
    // swapped QK^T: mfma(K,Q) -> lane holds S(q = q0+l15, kv = kv0 + sub*16 + lg*4 + r)
#pragma unroll
    for (int sub = 0; sub < 4; ++sub) {
      bf16x8 kf0 = *(const bf16x8*)(kt + (size_t)(sub * 16 + l15) * DHEAD + lg * 8);
      bf16x8 kf1 = *(const bf16x8*)(kt + (size_t)(sub * 16 + l15) * DHEAD + 32 + lg * 8);
      f32x4 z = {};
      z = mfma16(kf0, qf0, z);
      sc[sub] = mfma16(kf1, qf1, z);
    }
    // fixed-max softmax: p = exp2(s); denom deferred (per-lane partial, q is lane-local)
#pragma unroll
    for (int sub = 0; sub < 4; ++sub) {
      ushort4v pw;
#pragma unroll
      for (int r = 0; r < 4; ++r) {
        float p = exp2f(sc[sub][r]);
        lsum_p += p;
        pw[r] = f2bf(p);
      }
      *(ushort4v*)&P_lds[w][l15][sub * 16 + lg * 4] = pw;  // row-local packed b64 write
    }
    // PV: A-frag = P (m=q, k=kv), B-frag = V^T (n=dh, k=kv), same k-order both sides
#pragma unroll
    for (int c = 0; c < 2; ++c) {
      bf16x8 pf = *(const bf16x8*)&P_lds[w][l15][c * 32 + lg * 8];  // same-wave read
      const unsigned short* vt2 = vbase + kv0 + c * 32 + lg * 8;
#pragma unroll
      for (int t = 0; t < 4; ++t) {
        bf16x8 vf = *(const bf16x8*)(vt2 + (size_t)(t * 16 + l15) * S_LEN);
        oacc[t] = mfma16(pf, vf, oacc[t]);
      }
    }
  }

  // finish denom: reduce across the 4 lg groups (same l15 = same q)
  lsum_p += __shfl_xor(lsum_p, 16);
  lsum_p += __shfl_xor(lsum_p, 32);

  // write per-wave partials (fixed-max => partials combine by plain addition)
#pragma unroll
  for (int t = 0; t < 4; ++t)
#pragma unroll
    for (int r = 0; r < 4; ++r)
      part[w][lg * 4 + r][t * 16 + l15] = oacc[t][r];
  if (lane < 16) lsum_lds[w][l15] = lsum_p;
  __syncthreads();  // cross-wave combine barrier (stays)

  {
    int qr = tid >> 4, d0 = (tid & 15) << 2;
    f32x4 s = *(const f32x4*)&part[0][qr][d0];
    s += *(const f32x4*)&part[1][qr][d0];
    s += *(const f32x4*)&part[2][qr][d0];
    s += *(const f32x4*)&part[3][qr][d0];
    float l = lsum_lds[0][qr] + lsum_lds[1][qr] + lsum_lds[2][qr] + lsum_lds[3][qr];
    float inv = 1.0f / l;
    size_t idx = base + (size_t)(q0 + qr) * DHEAD + d0;
    f32x4 qv = *(const f32x4*)(qp32 + idx);
    f32x4 res = qv + s * inv;
    ushort4v hb;
#pragma unroll
    for (int j = 0; j < 4; ++j) hb[j] = f2bf(res[j]);
    *(ushort4v*)(head_bf + idx) = hb;  // bf16 head: residual + normalized PV
  }
}

// ---- out = head_bf[8192x64] @ wosumT^T [64x1024] + bo, via MFMA (K=64)
// Same fragment conventions as proj (A rows = m, B rows = n, verified C-layout).
__global__ __launch_bounds__(256) void out_kernel(
    const unsigned short* __restrict__ head_bf, const unsigned short* __restrict__ wosumT,
    const float* __restrict__ bo, float* __restrict__ out) {
  int bx = blockIdx.x;
  int m0 = (bx >> 3) << 6;  // 128 row-blocks of 64
  int c0 = (bx & 7) << 7;   // 8 col-blocks of 128
  int tid = threadIdx.x, lane = tid & 63, w = tid >> 6;
  int l15 = lane & 15, lg = lane >> 4;

  const unsigned short* ap = head_bf + (size_t)(m0 + w * 16 + l15) * DHEAD + lg * 8;
  bf16x8 af0 = *(const bf16x8*)ap;         // k = lg*8..+8
  bf16x8 af1 = *(const bf16x8*)(ap + 32);  // k = 32+lg*8..+8

  f32x4 acc[8] = {};
#pragma unroll
  for (int t = 0; t < 8; ++t) {
    const unsigned short* bp = wosumT + (size_t)(c0 + t * 16 + l15) * DHEAD + lg * 8;
    bf16x8 b0 = *(const bf16x8*)bp;
    bf16x8 b1 = *(const bf16x8*)(bp + 32);
    acc[t] = mfma16(af0, b0, acc[t]);
    acc[t] = mfma16(af1, b1, acc[t]);
  }
#pragma unroll
  for (int t = 0; t < 8; ++t) {
    int col = c0 + t * 16 + l15;
    float bias = bo[col];
#pragma unroll
    for (int r = 0; r < 4; ++r) {
      int row = m0 + w * 16 + lg * 4 + r;
      out[(size_t)row * 1024 + col] = acc[t][r] + bias;
    }
  }
}

extern "C" void kernel_launch(void* const* d_in, const int* in_sizes, int n_in,
                              void* d_out, int out_size, void* d_ws, size_t ws_size,
                              hipStream_t stream) {
  (void)in_sizes; (void)n_in; (void)out_size; (void)ws_size;
  const float* v = (const float*)d_in[0];
  const float* k = (const float*)d_in[1];
  const float* q = (const float*)d_in[2];
  const float* wi = (const float*)d_in[3];
  const float* Wo = (const float*)d_in[4];
  const float* bo = (const float*)d_in[5];
  float* out = (float*)d_out;
  char* ws = (char*)d_ws;

  float* qp32 = (float*)(ws + 0);                                // 2 MB
  unsigned short* head_bf = (unsigned short*)(ws + (2u << 20));  // 1 MB
  unsigned short* qp_bf = (unsigned short*)(ws + (4u << 20));    // 1 MB
  unsigned short* kp_bf = (unsigned short*)(ws + (5u << 20));    // 1 MB
  unsigned short* vpT = (unsigned short*)(ws + (6u << 20));      // 1 MB  [b][dh][kv]
  unsigned short* wiT = (unsigned short*)(ws + (7u << 20));      // 128 KB
  unsigned short* wosumT = (unsigned short*)(ws + (7u << 20) + (512u << 10));  // 128 KB
  unsigned short* xbf = (unsigned short*)(ws + (8u << 20));      // 48 MB [3][8192][1024] bf16

  prep_kernel<<<512, 256, 0, stream>>>(wi, Wo, wiT, wosumT);
  cvt_kernel<<<3072, 256, 0, stream>>>(q, k, v, xbf);
  proj_kernel<<<1536, 256, 0, stream>>>(xbf, wiT, qp32, qp_bf, kp_bf, vpT);
  attn_kernel<<<512, 256, 0, stream>>>(qp_bf, kp_bf, vpT, qp32, head_bf);
  out_kernel<<<1024, 256, 0, stream>>>(head_bf, wosumT, bo, out);
}

// Round 7
// 75.803 us; speedup vs baseline: 1.4283x; 1.4283x over previous
//
#include <hip/hip_runtime.h>

typedef __bf16 bf16x8 __attribute__((ext_vector_type(8)));
typedef float f32x4 __attribute__((ext_vector_type(4)));
typedef unsigned short ushort8 __attribute__((ext_vector_type(8)));
typedef unsigned short ushort4v __attribute__((ext_vector_type(4)));

#define S_LEN 2048
#define DMODEL 1024
#define DHEAD 64
#define QK_SCALE 0.18033688f  /* (1/8) * log2(e) */

static __device__ __forceinline__ unsigned short f2bf(float x) {
  __bf16 h = (__bf16)x;
  return __builtin_bit_cast(unsigned short, h);
}

static __device__ __forceinline__ f32x4 mfma16(bf16x8 a, bf16x8 b, f32x4 c) {
  return __builtin_amdgcn_mfma_f32_16x16x32_bf16(a, b, c, 0, 0, 0);
}

#define GLOAD_LDS(SRC, DST)                                                            \
  __builtin_amdgcn_global_load_lds(                                                    \
      (const __attribute__((address_space(1))) void*)(SRC),                            \
      (__attribute__((address_space(3))) void*)(DST), 16, 0, 0)

// ---- fused prep: wiT [64][1024] bf16  +  wosumT [1024][64] bf16
// wosumT[j][d] = sum_h Wo[h*64+d][j]  (tile(head,16)@Wo == head@Wo_sum; B-frag layout)
__global__ void prep_kernel(const float* __restrict__ wi, const float* __restrict__ Wo,
                            unsigned short* __restrict__ wiT,
                            unsigned short* __restrict__ wosumT) {
  int i = blockIdx.x * 256 + threadIdx.x;  // 131072 total
  if (i < 65536) {
    int n = i >> 10, kk = i & 1023;
    wiT[i] = f2bf(wi[(size_t)kk * DHEAD + n]);
  } else {
    int idx = i - 65536;
    int j = idx & 1023, d = idx >> 10;  // consecutive lanes -> consecutive j (coalesced)
    float s = 0.f;
#pragma unroll
    for (int h = 0; h < 16; ++h) s += Wo[(size_t)(h * 64 + d) * 1024 + j];
    wosumT[(size_t)j * 64 + d] = f2bf(s);
  }
}

// ---- projections: single-wave blocks, LDS DMA ring, counted vmcnt pipeline (r3 form).
// r0-r6 post-mortem: SIX structurally different read schedules (multi-wave LDS,
// register pipeline x2, DMA ring, memcpy-shaped, pure-streaming cvt) ALL read the
// 96MB fp32 inputs in ~42us (~2.3 TB/s read-side). That is this box's read wall --
// cvt (zero-LDS, VGPR 24, 55% occ, fully independent loads) proved it decisively.
// Strategy: read the 96MB exactly ONCE with the best-measured single-pass kernel
// (this r3 form, 41.2us) and spend effort after proj instead.
__global__ __launch_bounds__(64) void proj_kernel(
    const float* __restrict__ q, const float* __restrict__ k, const float* __restrict__ v,
    const unsigned short* __restrict__ wiT,
    float* __restrict__ qp32, unsigned short* __restrict__ qp_bf,
    unsigned short* __restrict__ kp_bf, unsigned short* __restrict__ vpT) {
  int bx = blockIdx.x;       // 1536 blocks: 512 per tensor
  int ten = bx >> 9;         // 0:q 1:k 2:v
  int m0 = (bx & 511) << 4;  // 16-row strip
  const float* x = (ten == 0) ? q : ((ten == 1) ? k : v);
  int lane = threadIdx.x;
  int l15 = lane & 15, lg = lane >> 4;

  __shared__ __align__(16) char As[4 * 2048];   // ring: [buf][row 0..15][128B ^ ((row&7)<<4)]
  __shared__ __align__(16) char Bs[4 * 4096];   // ring: [buf][n 0..63][64B ^ ((n&3)<<4)]
  __shared__ __align__(16) unsigned short vt[16][72];

  const char* xb = (const char*)x;
  const char* wb = (const char*)wiT;

  // Pre-swizzled per-lane global sources (dest is linear: lane i -> base + i*16).
  const char* pA0 = xb + (size_t)(m0 + (lane >> 3)) * 4096 + ((((lane & 7) ^ (lane >> 3))) << 4);
  const char* pA1 = pA0 + 8 * 4096;
  const char* pB = wb + (size_t)(lane >> 2) * 2048 + ((((lane & 3) ^ ((lane >> 2) & 3))) << 4);

  auto ISSUE = [&](int st) {
    int buf = st & 3;
    char* ad = As + buf * 2048;
    char* bd = Bs + buf * 4096;
    GLOAD_LDS(pA0 + st * 128, ad);
    GLOAD_LDS(pA1 + st * 128, ad + 1024);
#pragma unroll
    for (int j = 0; j < 4; ++j) GLOAD_LDS(pB + j * 32768 + st * 64, bd + j * 1024);
  };

  f32x4 acc[4] = {};
  int swA = (l15 & 7) << 4;
  int swB = (l15 & 3) << 4;

  auto COMP = [&](int kt) {
    const char* Ab = As + (kt & 3) * 2048 + l15 * 128;
    f32x4 a0 = *(const f32x4*)(Ab + ((lg * 32) ^ swA));
    f32x4 a1 = *(const f32x4*)(Ab + ((lg * 32 + 16) ^ swA));
    bf16x8 af;
    af[0] = (__bf16)a0[0]; af[1] = (__bf16)a0[1]; af[2] = (__bf16)a0[2]; af[3] = (__bf16)a0[3];
    af[4] = (__bf16)a1[0]; af[5] = (__bf16)a1[1]; af[6] = (__bf16)a1[2]; af[7] = (__bf16)a1[3];
    const char* Bb = Bs + (kt & 3) * 4096 + ((lg * 16) ^ swB) + l15 * 64;
#pragma unroll
    for (int t = 0; t < 4; ++t) {
      bf16x8 bfr = *(const bf16x8*)(Bb + t * 1024);
      acc[t] = mfma16(af, bfr, acc[t]);
    }
  };

  ISSUE(0);
  ISSUE(1);
  ISSUE(2);
#pragma unroll 1
  for (int kt = 0; kt < 29; ++kt) {
    ISSUE(kt + 3);
    asm volatile("s_waitcnt vmcnt(18)" ::: "memory");  // stage kt landed; 3 in flight
    __builtin_amdgcn_sched_barrier(0);
    COMP(kt);
    __builtin_amdgcn_sched_barrier(0);  // keep next ISSUE below this COMP's ds_reads
  }
  asm volatile("s_waitcnt vmcnt(12)" ::: "memory");
  __builtin_amdgcn_sched_barrier(0);
  COMP(29);
  asm volatile("s_waitcnt vmcnt(6)" ::: "memory");
  __builtin_amdgcn_sched_barrier(0);
  COMP(30);
  asm volatile("s_waitcnt vmcnt(0)" ::: "memory");
  __builtin_amdgcn_sched_barrier(0);
  COMP(31);

  if (ten == 2) {
    // transpose 16 kv-rows x 64 d through tiny LDS, store vpT [b][dh][kv]
#pragma unroll
    for (int t = 0; t < 4; ++t)
#pragma unroll
      for (int r = 0; r < 4; ++r)
        vt[lg * 4 + r][t * 16 + l15] = f2bf(acc[t][r]);
    __syncthreads();  // single-wave block: cheap
    int bq = m0 >> 11, kvb = m0 & 2047;
    unsigned short* dst = vpT + (size_t)bq * (DHEAD * S_LEN) + (size_t)lane * S_LEN + kvb;
    ushort8 o0, o1;
#pragma unroll
    for (int j = 0; j < 8; ++j) {
      o0[j] = vt[j][lane];
      o1[j] = vt[8 + j][lane];
    }
    *(ushort8*)dst = o0;
    *(ushort8*)(dst + 8) = o1;
  } else {
#pragma unroll
    for (int t = 0; t < 4; ++t) {
      int gc = t * 16 + l15;
#pragma unroll
      for (int r = 0; r < 4; ++r) {
        size_t idx = (size_t)(m0 + lg * 4 + r) * DHEAD + gc;
        float val = acc[t][r];
        if (ten == 0) {
          qp32[idx] = val;
          qp_bf[idx] = f2bf(val * QK_SCALE);
        } else {
          kp_bf[idx] = f2bf(val);
        }
      }
    }
  }
}

// ---- flash attention + FUSED output projection.
// Attention part unchanged (fixed-max softmax, 4-way KV split, no in-loop barriers).
// r7 change: instead of writing head_bf and re-reading it in a separate out_kernel,
// the combine parks head (16 rows x 64, bf16) in a 2.3KB LDS tile; each wave then
// computes its 256 output columns (A = head rows, B = L2-resident wosumT, same
// fragment conventions as the deleted out_kernel) and writes out + bias directly.
// Deletes: one launch, head_bf global round-trip, out_kernel's redundant A-loads.
__global__ __launch_bounds__(256) void attn_out_kernel(
    const unsigned short* __restrict__ qp_bf, const unsigned short* __restrict__ kp_bf,
    const unsigned short* __restrict__ vpT, const float* __restrict__ qp32,
    const unsigned short* __restrict__ wosumT, const float* __restrict__ bo,
    float* __restrict__ out) {
  int bx = blockIdx.x;
  int b = bx >> 7;
  int q0 = (bx & 127) << 4;
  int tid = threadIdx.x, lane = tid & 63, w = tid >> 6;
  int l15 = lane & 15, lg = lane >> 4;

  __shared__ __align__(16) unsigned short P_lds[4][16][72];  // per-wave P round-trip
  __shared__ __align__(16) float part[4][16][64];            // per-wave PV partials
  __shared__ float lsum_lds[4][16];                          // per-wave denom partials
  __shared__ __align__(16) unsigned short head_lds[16][72];  // combined head rows (bf16)

  size_t base = (size_t)b * (S_LEN * DHEAD);
  const unsigned short* qrow_p = qp_bf + base + (size_t)(q0 + l15) * DHEAD + lg * 8;
  bf16x8 qf0 = *(const bf16x8*)qrow_p;  // B-frag: n=q, k=dh
  bf16x8 qf1 = *(const bf16x8*)(qrow_p + 32);

  const unsigned short* vbase = vpT + (size_t)b * (DHEAD * S_LEN);

  f32x4 oacc[4] = {};
  float lsum_p = 0.f;  // per-lane partial denom for q = q0 + l15

  for (int it = 0; it < 8; ++it) {
    int kv0 = w * 512 + it * 64;
    const unsigned short* kt = kp_bf + base + (size_t)kv0 * DHEAD;
    f32x4 sc[4];
    // swapped QK^T: mfma(K,Q) -> lane holds S(q = q0+l15, kv = kv0 + sub*16 + lg*4 + r)
#pragma unroll
    for (int sub = 0; sub < 4; ++sub) {
      bf16x8 kf0 = *(const bf16x8*)(kt + (size_t)(sub * 16 + l15) * DHEAD + lg * 8);
      bf16x8 kf1 = *(const bf16x8*)(kt + (size_t)(sub * 16 + l15) * DHEAD + 32 + lg * 8);
      f32x4 z = {};
      z = mfma16(kf0, qf0, z);
      sc[sub] = mfma16(kf1, qf1, z);
    }
    // fixed-max softmax: p = exp2(s); denom deferred (per-lane partial, q is lane-local)
#pragma unroll
    for (int sub = 0; sub < 4; ++sub) {
      ushort4v pw;
#pragma unroll
      for (int r = 0; r < 4; ++r) {
        float p = exp2f(sc[sub][r]);
        lsum_p += p;
        pw[r] = f2bf(p);
      }
      *(ushort4v*)&P_lds[w][l15][sub * 16 + lg * 4] = pw;  // row-local packed b64 write
    }
    // PV: A-frag = P (m=q, k=kv), B-frag = V^T (n=dh, k=kv), same k-order both sides
#pragma unroll
    for (int c = 0; c < 2; ++c) {
      bf16x8 pf = *(const bf16x8*)&P_lds[w][l15][c * 32 + lg * 8];  // same-wave read
      const unsigned short* vt2 = vbase + kv0 + c * 32 + lg * 8;
#pragma unroll
      for (int t = 0; t < 4; ++t) {
        bf16x8 vf = *(const bf16x8*)(vt2 + (size_t)(t * 16 + l15) * S_LEN);
        oacc[t] = mfma16(pf, vf, oacc[t]);
      }
    }
  }

  // finish denom: reduce across the 4 lg groups (same l15 = same q)
  lsum_p += __shfl_xor(lsum_p, 16);
  lsum_p += __shfl_xor(lsum_p, 32);

  // write per-wave partials (fixed-max => partials combine by plain addition)
#pragma unroll
  for (int t = 0; t < 4; ++t)
#pragma unroll
    for (int r = 0; r < 4; ++r)
      part[w][lg * 4 + r][t * 16 + l15] = oacc[t][r];
  if (lane < 16) lsum_lds[w][l15] = lsum_p;
  __syncthreads();  // cross-wave combine barrier

  {
    int qr = tid >> 4, d0 = (tid & 15) << 2;
    f32x4 s = *(const f32x4*)&part[0][qr][d0];
    s += *(const f32x4*)&part[1][qr][d0];
    s += *(const f32x4*)&part[2][qr][d0];
    s += *(const f32x4*)&part[3][qr][d0];
    float l = lsum_lds[0][qr] + lsum_lds[1][qr] + lsum_lds[2][qr] + lsum_lds[3][qr];
    float inv = 1.0f / l;
    size_t idx = base + (size_t)(q0 + qr) * DHEAD + d0;
    f32x4 qv = *(const f32x4*)(qp32 + idx);
    f32x4 res = qv + s * inv;
    ushort4v hb;
#pragma unroll
    for (int j = 0; j < 4; ++j) hb[j] = f2bf(res[j]);
    *(ushort4v*)&head_lds[qr][d0] = hb;
  }
  __syncthreads();  // head ready for all waves

  // ---- fused out: out[q0+lg*4+r][w*256 + t*16 + l15] over K=64
  bf16x8 af0 = *(const bf16x8*)&head_lds[l15][lg * 8];       // A row = l15, k = lg*8
  bf16x8 af1 = *(const bf16x8*)&head_lds[l15][32 + lg * 8];  // k = 32+lg*8
  size_t orow = ((size_t)b * S_LEN + q0 + lg * 4) * 1024;
  int c0 = w * 256;
#pragma unroll
  for (int t = 0; t < 16; ++t) {
    int col = c0 + t * 16 + l15;
    const unsigned short* bp = wosumT + (size_t)col * 64 + lg * 8;
    bf16x8 b0 = *(const bf16x8*)bp;
    bf16x8 b1 = *(const bf16x8*)(bp + 32);
    f32x4 acc = {};
    acc = mfma16(af0, b0, acc);
    acc = mfma16(af1, b1, acc);
    float bias = bo[col];
#pragma unroll
    for (int r = 0; r < 4; ++r) out[orow + (size_t)r * 1024 + col] = acc[r] + bias;
  }
}

extern "C" void kernel_launch(void* const* d_in, const int* in_sizes, int n_in,
                              void* d_out, int out_size, void* d_ws, size_t ws_size,
                              hipStream_t stream) {
  (void)in_sizes; (void)n_in; (void)out_size; (void)ws_size;
  const float* v = (const float*)d_in[0];
  const float* k = (const float*)d_in[1];
  const float* q = (const float*)d_in[2];
  const float* wi = (const float*)d_in[3];
  const float* Wo = (const float*)d_in[4];
  const float* bo = (const float*)d_in[5];
  float* out = (float*)d_out;
  char* ws = (char*)d_ws;

  float* qp32 = (float*)(ws + 0);                                // 2 MB
  unsigned short* qp_bf = (unsigned short*)(ws + (4u << 20));    // 1 MB
  unsigned short* kp_bf = (unsigned short*)(ws + (5u << 20));    // 1 MB
  unsigned short* vpT = (unsigned short*)(ws + (6u << 20));      // 1 MB  [b][dh][kv]
  unsigned short* wiT = (unsigned short*)(ws + (7u << 20));      // 128 KB
  unsigned short* wosumT = (unsigned short*)(ws + (7u << 20) + (512u << 10));  // 128 KB

  prep_kernel<<<512, 256, 0, stream>>>(wi, Wo, wiT, wosumT);
  proj_kernel<<<1536, 64, 0, stream>>>(q, k, v, wiT, qp32, qp_bf, kp_bf, vpT);
  attn_out_kernel<<<512, 256, 0, stream>>>(qp_bf, kp_bf, vpT, qp32, wosumT, bo, out);
}

// Round 8
// 72.486 us; speedup vs baseline: 1.4937x; 1.0458x over previous
//
#include <hip/hip_runtime.h>

typedef __bf16 bf16x8 __attribute__((ext_vector_type(8)));
typedef float f32x4 __attribute__((ext_vector_type(4)));
typedef unsigned short ushort8 __attribute__((ext_vector_type(8)));
typedef unsigned short ushort4v __attribute__((ext_vector_type(4)));

#define S_LEN 2048
#define DMODEL 1024
#define DHEAD 64
#define QK_SCALE 0.18033688f  /* (1/8) * log2(e) */

static __device__ __forceinline__ unsigned short f2bf(float x) {
  __bf16 h = (__bf16)x;
  return __builtin_bit_cast(unsigned short, h);
}

static __device__ __forceinline__ f32x4 mfma16(bf16x8 a, bf16x8 b, f32x4 c) {
  return __builtin_amdgcn_mfma_f32_16x16x32_bf16(a, b, c, 0, 0, 0);
}

#define GLOAD_LDS(SRC, DST)                                                            \
  __builtin_amdgcn_global_load_lds(                                                    \
      (const __attribute__((address_space(1))) void*)(SRC),                            \
      (__attribute__((address_space(3))) void*)(DST), 16, 0, 0)

// ---- fused prep: wiT [64][1024] bf16  +  wosumT [1024][64] bf16
// wosumT[j][d] = sum_h Wo[h*64+d][j]  (tile(head,16)@Wo == head@Wo_sum; B-frag layout)
__global__ void prep_kernel(const float* __restrict__ wi, const float* __restrict__ Wo,
                            unsigned short* __restrict__ wiT,
                            unsigned short* __restrict__ wosumT) {
  int i = blockIdx.x * 256 + threadIdx.x;  // 131072 total
  if (i < 65536) {
    int n = i >> 10, kk = i & 1023;
    wiT[i] = f2bf(wi[(size_t)kk * DHEAD + n]);
  } else {
    int idx = i - 65536;
    int j = idx & 1023, d = idx >> 10;  // consecutive lanes -> consecutive j (coalesced)
    float s = 0.f;
#pragma unroll
    for (int h = 0; h < 16; ++h) s += Wo[(size_t)(h * 64 + d) * 1024 + j];
    wosumT[(size_t)j * 64 + d] = f2bf(s);
  }
}

// ---- projections: single-wave blocks, LDS DMA ring, counted vmcnt pipeline (r3 form).
// r0-r6 post-mortem: SIX structurally different read schedules ALL read the 96MB fp32
// inputs in ~42us (~2.3 TB/s read-side) -- this box's read wall, proven decisively by
// the pure-streaming cvt probe (r6). FROZEN: read the 96MB exactly once in this form.
__global__ __launch_bounds__(64) void proj_kernel(
    const float* __restrict__ q, const float* __restrict__ k, const float* __restrict__ v,
    const unsigned short* __restrict__ wiT,
    float* __restrict__ qp32, unsigned short* __restrict__ qp_bf,
    unsigned short* __restrict__ kp_bf, unsigned short* __restrict__ vpT) {
  int bx = blockIdx.x;       // 1536 blocks: 512 per tensor
  int ten = bx >> 9;         // 0:q 1:k 2:v
  int m0 = (bx & 511) << 4;  // 16-row strip
  const float* x = (ten == 0) ? q : ((ten == 1) ? k : v);
  int lane = threadIdx.x;
  int l15 = lane & 15, lg = lane >> 4;

  __shared__ __align__(16) char As[4 * 2048];   // ring: [buf][row 0..15][128B ^ ((row&7)<<4)]
  __shared__ __align__(16) char Bs[4 * 4096];   // ring: [buf][n 0..63][64B ^ ((n&3)<<4)]
  __shared__ __align__(16) unsigned short vt[16][72];

  const char* xb = (const char*)x;
  const char* wb = (const char*)wiT;

  const char* pA0 = xb + (size_t)(m0 + (lane >> 3)) * 4096 + ((((lane & 7) ^ (lane >> 3))) << 4);
  const char* pA1 = pA0 + 8 * 4096;
  const char* pB = wb + (size_t)(lane >> 2) * 2048 + ((((lane & 3) ^ ((lane >> 2) & 3))) << 4);

  auto ISSUE = [&](int st) {
    int buf = st & 3;
    char* ad = As + buf * 2048;
    char* bd = Bs + buf * 4096;
    GLOAD_LDS(pA0 + st * 128, ad);
    GLOAD_LDS(pA1 + st * 128, ad + 1024);
#pragma unroll
    for (int j = 0; j < 4; ++j) GLOAD_LDS(pB + j * 32768 + st * 64, bd + j * 1024);
  };

  f32x4 acc[4] = {};
  int swA = (l15 & 7) << 4;
  int swB = (l15 & 3) << 4;

  auto COMP = [&](int kt) {
    const char* Ab = As + (kt & 3) * 2048 + l15 * 128;
    f32x4 a0 = *(const f32x4*)(Ab + ((lg * 32) ^ swA));
    f32x4 a1 = *(const f32x4*)(Ab + ((lg * 32 + 16) ^ swA));
    bf16x8 af;
    af[0] = (__bf16)a0[0]; af[1] = (__bf16)a0[1]; af[2] = (__bf16)a0[2]; af[3] = (__bf16)a0[3];
    af[4] = (__bf16)a1[0]; af[5] = (__bf16)a1[1]; af[6] = (__bf16)a1[2]; af[7] = (__bf16)a1[3];
    const char* Bb = Bs + (kt & 3) * 4096 + ((lg * 16) ^ swB) + l15 * 64;
#pragma unroll
    for (int t = 0; t < 4; ++t) {
      bf16x8 bfr = *(const bf16x8*)(Bb + t * 1024);
      acc[t] = mfma16(af, bfr, acc[t]);
    }
  };

  ISSUE(0);
  ISSUE(1);
  ISSUE(2);
#pragma unroll 1
  for (int kt = 0; kt < 29; ++kt) {
    ISSUE(kt + 3);
    asm volatile("s_waitcnt vmcnt(18)" ::: "memory");  // stage kt landed; 3 in flight
    __builtin_amdgcn_sched_barrier(0);
    COMP(kt);
    __builtin_amdgcn_sched_barrier(0);  // keep next ISSUE below this COMP's ds_reads
  }
  asm volatile("s_waitcnt vmcnt(12)" ::: "memory");
  __builtin_amdgcn_sched_barrier(0);
  COMP(29);
  asm volatile("s_waitcnt vmcnt(6)" ::: "memory");
  __builtin_amdgcn_sched_barrier(0);
  COMP(30);
  asm volatile("s_waitcnt vmcnt(0)" ::: "memory");
  __builtin_amdgcn_sched_barrier(0);
  COMP(31);

  if (ten == 2) {
    // transpose 16 kv-rows x 64 d through tiny LDS, store vpT [b][dh][kv]
#pragma unroll
    for (int t = 0; t < 4; ++t)
#pragma unroll
      for (int r = 0; r < 4; ++r)
        vt[lg * 4 + r][t * 16 + l15] = f2bf(acc[t][r]);
    __syncthreads();  // single-wave block: cheap
    int bq = m0 >> 11, kvb = m0 & 2047;
    unsigned short* dst = vpT + (size_t)bq * (DHEAD * S_LEN) + (size_t)lane * S_LEN + kvb;
    ushort8 o0, o1;
#pragma unroll
    for (int j = 0; j < 8; ++j) {
      o0[j] = vt[j][lane];
      o1[j] = vt[8 + j][lane];
    }
    *(ushort8*)dst = o0;
    *(ushort8*)(dst + 8) = o1;
  } else {
#pragma unroll
    for (int t = 0; t < 4; ++t) {
      int gc = t * 16 + l15;
#pragma unroll
      for (int r = 0; r < 4; ++r) {
        size_t idx = (size_t)(m0 + lg * 4 + r) * DHEAD + gc;
        float val = acc[t][r];
        if (ten == 0) {
          qp32[idx] = val;
          qp_bf[idx] = f2bf(val * QK_SCALE);
        } else {
          kp_bf[idx] = f2bf(val);
        }
      }
    }
  }
}

// ---- flash attention + fused output projection, ILP edition.
// r7 post-mortem: VGPR_Count=48 (occupancy-targeted RA) serialized the 128 L2
// loads/wave -> 47us latency-bound (MfmaUtil 4%, VALU 11%). Grid = exactly
// 2 blocks/CU = 2 waves/SIMD, so reserving regs for 8 waves/SIMD bought nothing.
// Fix: __launch_bounds__(256,2) unlocks ~256 VGPR/wave; loads batched into
// static-indexed arrays (all 8 K-frags, then MFMAs; all 8 V-frags issued BEFORE
// the softmax so they hide under the exp chain). Intra-iteration ILP only --
// no cross-iteration register pipeline (r1/r2 lesson).
__global__ __launch_bounds__(256, 2) void attn_out_kernel(
    const unsigned short* __restrict__ qp_bf, const unsigned short* __restrict__ kp_bf,
    const unsigned short* __restrict__ vpT, const float* __restrict__ qp32,
    const unsigned short* __restrict__ wosumT, const float* __restrict__ bo,
    float* __restrict__ out) {
  int bx = blockIdx.x;
  int b = bx >> 7;
  int q0 = (bx & 127) << 4;
  int tid = threadIdx.x, lane = tid & 63, w = tid >> 6;
  int l15 = lane & 15, lg = lane >> 4;

  __shared__ __align__(16) unsigned short P_lds[4][16][72];  // per-wave P round-trip
  __shared__ __align__(16) float part[4][16][64];            // per-wave PV partials
  __shared__ float lsum_lds[4][16];                          // per-wave denom partials
  __shared__ __align__(16) unsigned short head_lds[16][72];  // combined head rows (bf16)

  size_t base = (size_t)b * (S_LEN * DHEAD);
  const unsigned short* qrow_p = qp_bf + base + (size_t)(q0 + l15) * DHEAD + lg * 8;
  bf16x8 qf0 = *(const bf16x8*)qrow_p;  // B-frag: n=q, k=dh
  bf16x8 qf1 = *(const bf16x8*)(qrow_p + 32);

  const unsigned short* vbase = vpT + (size_t)b * (DHEAD * S_LEN);

  f32x4 oacc[4] = {};
  float lsum_p = 0.f;  // per-lane partial denom for q = q0 + l15

  for (int it = 0; it < 8; ++it) {
    int kv0 = w * 512 + it * 64;
    const unsigned short* kt = kp_bf + base + (size_t)kv0 * DHEAD;

    // batch-issue all 8 K-frag loads (independent; fill the vmcnt queue)
    bf16x8 kf[8];
#pragma unroll
    for (int sub = 0; sub < 4; ++sub) {
      const unsigned short* kp_ = kt + (size_t)(sub * 16 + l15) * DHEAD + lg * 8;
      kf[2 * sub] = *(const bf16x8*)kp_;
      kf[2 * sub + 1] = *(const bf16x8*)(kp_ + 32);
    }
    // batch-issue all 8 V-frag loads too -- they are score-independent and
    // their latency hides under QK^T + softmax below.
    bf16x8 vf[8];
#pragma unroll
    for (int c = 0; c < 2; ++c) {
      const unsigned short* vt2 = vbase + kv0 + c * 32 + lg * 8;
#pragma unroll
      for (int t = 0; t < 4; ++t)
        vf[c * 4 + t] = *(const bf16x8*)(vt2 + (size_t)(t * 16 + l15) * S_LEN);
    }

    // swapped QK^T: mfma(K,Q) -> lane holds S(q = q0+l15, kv = kv0 + sub*16 + lg*4 + r)
    f32x4 sc[4];
#pragma unroll
    for (int sub = 0; sub < 4; ++sub) {
      f32x4 z = {};
      z = mfma16(kf[2 * sub], qf0, z);
      sc[sub] = mfma16(kf[2 * sub + 1], qf1, z);
    }
    // fixed-max softmax: p = exp2(s); denom deferred (per-lane partial, q is lane-local)
#pragma unroll
    for (int sub = 0; sub < 4; ++sub) {
      ushort4v pw;
#pragma unroll
      for (int r = 0; r < 4; ++r) {
        float p = exp2f(sc[sub][r]);
        lsum_p += p;
        pw[r] = f2bf(p);
      }
      *(ushort4v*)&P_lds[w][l15][sub * 16 + lg * 4] = pw;  // row-local packed b64 write
    }
    // PV: A-frag = P (m=q, k=kv), B-frag = V^T (n=dh, k=kv), same k-order both sides
#pragma unroll
    for (int c = 0; c < 2; ++c) {
      bf16x8 pf = *(const bf16x8*)&P_lds[w][l15][c * 32 + lg * 8];  // same-wave read
#pragma unroll
      for (int t = 0; t < 4; ++t) oacc[t] = mfma16(pf, vf[c * 4 + t], oacc[t]);
    }
  }

  // finish denom: reduce across the 4 lg groups (same l15 = same q)
  lsum_p += __shfl_xor(lsum_p, 16);
  lsum_p += __shfl_xor(lsum_p, 32);

  // write per-wave partials (fixed-max => partials combine by plain addition)
#pragma unroll
  for (int t = 0; t < 4; ++t)
#pragma unroll
    for (int r = 0; r < 4; ++r)
      part[w][lg * 4 + r][t * 16 + l15] = oacc[t][r];
  if (lane < 16) lsum_lds[w][l15] = lsum_p;
  __syncthreads();  // cross-wave combine barrier

  {
    int qr = tid >> 4, d0 = (tid & 15) << 2;
    f32x4 s = *(const f32x4*)&part[0][qr][d0];
    s += *(const f32x4*)&part[1][qr][d0];
    s += *(const f32x4*)&part[2][qr][d0];
    s += *(const f32x4*)&part[3][qr][d0];
    float l = lsum_lds[0][qr] + lsum_lds[1][qr] + lsum_lds[2][qr] + lsum_lds[3][qr];
    float inv = 1.0f / l;
    size_t idx = base + (size_t)(q0 + qr) * DHEAD + d0;
    f32x4 qv = *(const f32x4*)(qp32 + idx);
    f32x4 res = qv + s * inv;
    ushort4v hb;
#pragma unroll
    for (int j = 0; j < 4; ++j) hb[j] = f2bf(res[j]);
    *(ushort4v*)&head_lds[qr][d0] = hb;
  }
  __syncthreads();  // head ready for all waves

  // ---- fused out: out[q0+lg*4+r][w*256 + t*16 + l15] over K=64
  bf16x8 af0 = *(const bf16x8*)&head_lds[l15][lg * 8];       // A row = l15, k = lg*8
  bf16x8 af1 = *(const bf16x8*)&head_lds[l15][32 + lg * 8];  // k = 32+lg*8
  size_t orow = ((size_t)b * S_LEN + q0 + lg * 4) * 1024;
  int c0 = w * 256;
#pragma unroll
  for (int t = 0; t < 16; ++t) {
    int col = c0 + t * 16 + l15;
    const unsigned short* bp = wosumT + (size_t)col * 64 + lg * 8;
    bf16x8 b0 = *(const bf16x8*)bp;
    bf16x8 b1 = *(const bf16x8*)(bp + 32);
    f32x4 acc = {};
    acc = mfma16(af0, b0, acc);
    acc = mfma16(af1, b1, acc);
    float bias = bo[col];
#pragma unroll
    for (int r = 0; r < 4; ++r) out[orow + (size_t)r * 1024 + col] = acc[r] + bias;
  }
}

extern "C" void kernel_launch(void* const* d_in, const int* in_sizes, int n_in,
                              void* d_out, int out_size, void* d_ws, size_t ws_size,
                              hipStream_t stream) {
  (void)in_sizes; (void)n_in; (void)out_size; (void)ws_size;
  const float* v = (const float*)d_in[0];
  const float* k = (const float*)d_in[1];
  const float* q = (const float*)d_in[2];
  const float* wi = (const float*)d_in[3];
  const float* Wo = (const float*)d_in[4];
  const float* bo = (const float*)d_in[5];
  float* out = (float*)d_out;
  char* ws = (char*)d_ws;

  float* qp32 = (float*)(ws + 0);                                // 2 MB
  unsigned short* qp_bf = (unsigned short*)(ws + (4u << 20));    // 1 MB
  unsigned short* kp_bf = (unsigned short*)(ws + (5u << 20));    // 1 MB
  unsigned short* vpT = (unsigned short*)(ws + (6u << 20));      // 1 MB  [b][dh][kv]
  unsigned short* wiT = (unsigned short*)(ws + (7u << 20));      // 128 KB
  unsigned short* wosumT = (unsigned short*)(ws + (7u << 20) + (512u << 10));  // 128 KB

  prep_kernel<<<512, 256, 0, stream>>>(wi, Wo, wiT, wosumT);
  proj_kernel<<<1536, 64, 0, stream>>>(q, k, v, wiT, qp32, qp_bf, kp_bf, vpT);
  attn_out_kernel<<<512, 256, 0, stream>>>(qp_bf, kp_bf, vpT, qp32, wosumT, bo, out);
}

// Round 9
// 57.338 us; speedup vs baseline: 1.8882x; 1.2642x over previous
//
#include <hip/hip_runtime.h>

typedef __bf16 bf16x8 __attribute__((ext_vector_type(8)));
typedef float f32x4 __attribute__((ext_vector_type(4)));
typedef unsigned short ushort8 __attribute__((ext_vector_type(8)));
typedef unsigned short ushort4v __attribute__((ext_vector_type(4)));

#define S_LEN 2048
#define DMODEL 1024
#define DHEAD 64
#define QK_SCALE 0.18033688f  /* (1/8) * log2(e) */

static __device__ __forceinline__ unsigned short f2bf(float x) {
  __bf16 h = (__bf16)x;
  return __builtin_bit_cast(unsigned short, h);
}

static __device__ __forceinline__ f32x4 mfma16(bf16x8 a, bf16x8 b, f32x4 c) {
  return __builtin_amdgcn_mfma_f32_16x16x32_bf16(a, b, c, 0, 0, 0);
}

#define GLOAD_LDS(SRC, DST)                                                            \
  __builtin_amdgcn_global_load_lds(                                                    \
      (const __attribute__((address_space(1))) void*)(SRC),                            \
      (__attribute__((address_space(3))) void*)(DST), 16, 0, 0)

// ---- fused prep: wiT [64][1024] bf16  +  wosumT [1024][64] bf16
__global__ void prep_kernel(const float* __restrict__ wi, const float* __restrict__ Wo,
                            unsigned short* __restrict__ wiT,
                            unsigned short* __restrict__ wosumT) {
  int i = blockIdx.x * 256 + threadIdx.x;  // 131072 total
  if (i < 65536) {
    int n = i >> 10, kk = i & 1023;
    wiT[i] = f2bf(wi[(size_t)kk * DHEAD + n]);
  } else {
    int idx = i - 65536;
    int j = idx & 1023, d = idx >> 10;
    float s = 0.f;
#pragma unroll
    for (int h = 0; h < 16; ++h) s += Wo[(size_t)(h * 64 + d) * 1024 + j];
    wosumT[(size_t)j * 64 + d] = f2bf(s);
  }
}

// ---- projections (r3 form, FROZEN: 96MB fp32 read wall ~42us proven by r6 cvt probe).
// Only change: V epilogue writes TILED vpT layout [b][kvblk=32][dh=64][kvin=64] so each
// attn wave's V-tile is 8KB contiguous (r8 post-mortem: 4KB-strided V reads were
// 16-way transaction splits -- the attn serializer).
__global__ __launch_bounds__(64) void proj_kernel(
    const float* __restrict__ q, const float* __restrict__ k, const float* __restrict__ v,
    const unsigned short* __restrict__ wiT,
    float* __restrict__ qp32, unsigned short* __restrict__ qp_bf,
    unsigned short* __restrict__ kp_bf, unsigned short* __restrict__ vpT) {
  int bx = blockIdx.x;       // 1536 blocks: 512 per tensor
  int ten = bx >> 9;         // 0:q 1:k 2:v
  int m0 = (bx & 511) << 4;  // 16-row strip
  const float* x = (ten == 0) ? q : ((ten == 1) ? k : v);
  int lane = threadIdx.x;
  int l15 = lane & 15, lg = lane >> 4;

  __shared__ __align__(16) char As[4 * 2048];
  __shared__ __align__(16) char Bs[4 * 4096];
  __shared__ __align__(16) unsigned short vt[16][72];

  const char* xb = (const char*)x;
  const char* wb = (const char*)wiT;

  const char* pA0 = xb + (size_t)(m0 + (lane >> 3)) * 4096 + ((((lane & 7) ^ (lane >> 3))) << 4);
  const char* pA1 = pA0 + 8 * 4096;
  const char* pB = wb + (size_t)(lane >> 2) * 2048 + ((((lane & 3) ^ ((lane >> 2) & 3))) << 4);

  auto ISSUE = [&](int st) {
    int buf = st & 3;
    char* ad = As + buf * 2048;
    char* bd = Bs + buf * 4096;
    GLOAD_LDS(pA0 + st * 128, ad);
    GLOAD_LDS(pA1 + st * 128, ad + 1024);
#pragma unroll
    for (int j = 0; j < 4; ++j) GLOAD_LDS(pB + j * 32768 + st * 64, bd + j * 1024);
  };

  f32x4 acc[4] = {};
  int swA = (l15 & 7) << 4;
  int swB = (l15 & 3) << 4;

  auto COMP = [&](int kt) {
    const char* Ab = As + (kt & 3) * 2048 + l15 * 128;
    f32x4 a0 = *(const f32x4*)(Ab + ((lg * 32) ^ swA));
    f32x4 a1 = *(const f32x4*)(Ab + ((lg * 32 + 16) ^ swA));
    bf16x8 af;
    af[0] = (__bf16)a0[0]; af[1] = (__bf16)a0[1]; af[2] = (__bf16)a0[2]; af[3] = (__bf16)a0[3];
    af[4] = (__bf16)a1[0]; af[5] = (__bf16)a1[1]; af[6] = (__bf16)a1[2]; af[7] = (__bf16)a1[3];
    const char* Bb = Bs + (kt & 3) * 4096 + ((lg * 16) ^ swB) + l15 * 64;
#pragma unroll
    for (int t = 0; t < 4; ++t) {
      bf16x8 bfr = *(const bf16x8*)(Bb + t * 1024);
      acc[t] = mfma16(af, bfr, acc[t]);
    }
  };

  ISSUE(0);
  ISSUE(1);
  ISSUE(2);
#pragma unroll 1
  for (int kt = 0; kt < 29; ++kt) {
    ISSUE(kt + 3);
    asm volatile("s_waitcnt vmcnt(18)" ::: "memory");
    __builtin_amdgcn_sched_barrier(0);
    COMP(kt);
    __builtin_amdgcn_sched_barrier(0);
  }
  asm volatile("s_waitcnt vmcnt(12)" ::: "memory");
  __builtin_amdgcn_sched_barrier(0);
  COMP(29);
  asm volatile("s_waitcnt vmcnt(6)" ::: "memory");
  __builtin_amdgcn_sched_barrier(0);
  COMP(30);
  asm volatile("s_waitcnt vmcnt(0)" ::: "memory");
  __builtin_amdgcn_sched_barrier(0);
  COMP(31);

  if (ten == 2) {
#pragma unroll
    for (int t = 0; t < 4; ++t)
#pragma unroll
      for (int r = 0; r < 4; ++r)
        vt[lg * 4 + r][t * 16 + l15] = f2bf(acc[t][r]);
    __syncthreads();  // single-wave block: cheap
    int bq = m0 >> 11, kvb = m0 & 2047;
    // TILED vpT: [b][kvb>>6][dh=lane][kvin], tile = 4096 shorts (8KB contiguous)
    unsigned short* dst = vpT + (size_t)bq * 131072 + (size_t)(kvb >> 6) * 4096 +
                          (size_t)lane * 64 + (kvb & 63);
    ushort8 o0, o1;
#pragma unroll
    for (int j = 0; j < 8; ++j) {
      o0[j] = vt[j][lane];
      o1[j] = vt[8 + j][lane];
    }
    *(ushort8*)dst = o0;
    *(ushort8*)(dst + 8) = o1;
  } else {
#pragma unroll
    for (int t = 0; t < 4; ++t) {
      int gc = t * 16 + l15;
#pragma unroll
      for (int r = 0; r < 4; ++r) {
        size_t idx = (size_t)(m0 + lg * 4 + r) * DHEAD + gc;
        float val = acc[t][r];
        if (ten == 0) {
          qp32[idx] = val;
          qp_bf[idx] = f2bf(val * QK_SCALE);
        } else {
          kp_bf[idx] = f2bf(val);
        }
      }
    }
  }
}

// ---- flash attention + fused out, LDS-staged K/V edition.
// r8 post-mortem: frag loads from global were 16-way transaction splits (128B/4KB row
// strides) -> ~256 scattered 64B L2 transactions per wave-iter -> TA/L2-transaction
// bound (~28us true, all pipes idle). Fix: per-wave K-tile (8KB contiguous in kp_bf)
// and V-tile (8KB contiguous in tiled vpT) staged via 8+8 global_load_lds DMAs
// (pre-swizzled source, linear dest); frags become conflict-free swizzled ds_read_b128.
// T3/T4 pipeline: QK(it) overlaps V(it) flight; K(it+1) issued after QK; V(it+1) after
// PV; counted vmcnt(8), vmcnt(0) only at it=7. Wave-local => still no in-loop barriers.
// part/head alias the tiles post-loop: LDS 73KB -> 2 blocks/CU.
__global__ __launch_bounds__(256, 2) void attn_out_kernel(
    const unsigned short* __restrict__ qp_bf, const unsigned short* __restrict__ kp_bf,
    const unsigned short* __restrict__ vpT, const float* __restrict__ qp32,
    const unsigned short* __restrict__ wosumT, const float* __restrict__ bo,
    float* __restrict__ out) {
  int bx = blockIdx.x;
  int b = bx >> 7;
  int q0 = (bx & 127) << 4;
  int tid = threadIdx.x, lane = tid & 63, w = tid >> 6;
  int l15 = lane & 15, lg = lane >> 4;
  int r8 = lane >> 3, c8 = lane & 7;

  __shared__ __align__(16) char smem[74752];
  char* Kt = smem + w * 16384;        // wave-local K tile [64 kv][128B], row-XOR swz
  char* Vt = Kt + 8192;               // wave-local V tile [64 dh][128B], row-XOR swz
  unsigned short(*P_w)[72] = (unsigned short(*)[72])(smem + 65536 + w * 2304);
  float* part_w = (float*)Kt;         // post-loop alias: [16][64] f32
  float* lsum_w = (float*)(Kt + 4096);
  unsigned short(*head_lds)[72] = (unsigned short(*)[72])(smem + 65536);

  size_t base = (size_t)b * (S_LEN * DHEAD);
  const unsigned short* qrow_p = qp_bf + base + (size_t)(q0 + l15) * DHEAD + lg * 8;
  bf16x8 qf0 = *(const bf16x8*)qrow_p;
  bf16x8 qf1 = *(const bf16x8*)(qrow_p + 32);

  // pre-swizzled DMA sources (dest linear: lane -> +lane*16 within each 1KB)
  const char* pK = (const char*)(kp_bf + base) + r8 * 128 + ((c8 ^ r8) << 4);
  const char* pV = (const char*)vpT + (size_t)b * 262144 + r8 * 128 + ((c8 ^ r8) << 4);

  auto KISSUE = [&](int it2) {
    const char* s = pK + (size_t)(w * 512 + it2 * 64) * 128;
#pragma unroll
    for (int j = 0; j < 8; ++j) GLOAD_LDS(s + j * 1024, Kt + j * 1024);
  };
  auto VISSUE = [&](int it2) {
    const char* s = pV + (size_t)(w * 8 + it2) * 8192;
#pragma unroll
    for (int j = 0; j < 8; ++j) GLOAD_LDS(s + j * 1024, Vt + j * 1024);
  };

  f32x4 oacc[4] = {};
  float lsum_p = 0.f;
  int swz = (l15 & 7) << 4;

  KISSUE(0);
  VISSUE(0);
#pragma unroll
  for (int it = 0; it < 8; ++it) {
    // K(it) landed (V(it) still in flight)
    asm volatile("s_waitcnt vmcnt(8)" ::: "memory");
    __builtin_amdgcn_sched_barrier(0);
    f32x4 sc[4];
#pragma unroll
    for (int sub = 0; sub < 4; ++sub) {
      const char* kr = Kt + (sub * 16 + l15) * 128;
      bf16x8 kf0 = *(const bf16x8*)(kr + ((lg * 16) ^ swz));
      bf16x8 kf1 = *(const bf16x8*)(kr + ((64 + lg * 16) ^ swz));
      f32x4 z = {};
      z = mfma16(kf0, qf0, z);
      sc[sub] = mfma16(kf1, qf1, z);
    }
    // kf reads complete (MFMA consumed them); safe to overwrite Kt
    asm volatile("s_waitcnt lgkmcnt(0)" ::: "memory");
    __builtin_amdgcn_sched_barrier(0);
    if (it < 7) KISSUE(it + 1);
    // softmax while V(it) (and K(it+1)) fly
#pragma unroll
    for (int sub = 0; sub < 4; ++sub) {
      ushort4v pw;
#pragma unroll
      for (int r = 0; r < 4; ++r) {
        float p = exp2f(sc[sub][r]);
        lsum_p += p;
        pw[r] = f2bf(p);
      }
      *(ushort4v*)&P_w[l15][sub * 16 + lg * 4] = pw;
    }
    // V(it) landed (K(it+1) keeps flying)
    if (it < 7) {
      asm volatile("s_waitcnt vmcnt(8)" ::: "memory");
    } else {
      asm volatile("s_waitcnt vmcnt(0)" ::: "memory");
    }
    __builtin_amdgcn_sched_barrier(0);
#pragma unroll
    for (int c = 0; c < 2; ++c) {
      bf16x8 pf = *(const bf16x8*)&P_w[l15][c * 32 + lg * 8];
#pragma unroll
      for (int t = 0; t < 4; ++t) {
        const char* vr = Vt + (t * 16 + l15) * 128;
        bf16x8 vf = *(const bf16x8*)(vr + ((c * 64 + lg * 16) ^ swz));
        oacc[t] = mfma16(pf, vf, oacc[t]);
      }
    }
    // vf reads complete; safe to overwrite Vt
    asm volatile("s_waitcnt lgkmcnt(0)" ::: "memory");
    __builtin_amdgcn_sched_barrier(0);
    if (it < 7) VISSUE(it + 1);
  }

  // finish denom: reduce across the 4 lg groups (same l15 = same q)
  lsum_p += __shfl_xor(lsum_p, 16);
  lsum_p += __shfl_xor(lsum_p, 32);

  // per-wave partials into own (now free) K-tile region
#pragma unroll
  for (int t = 0; t < 4; ++t)
#pragma unroll
    for (int r = 0; r < 4; ++r)
      part_w[(lg * 4 + r) * 64 + t * 16 + l15] = oacc[t][r];
  if (lane < 16) lsum_w[l15] = lsum_p;
  __syncthreads();  // cross-wave combine barrier

  {
    int qr = tid >> 4, d0 = (tid & 15) << 2;
    f32x4 s = *(const f32x4*)(smem + 0 * 16384 + (qr * 64 + d0) * 4);
    s += *(const f32x4*)(smem + 1 * 16384 + (qr * 64 + d0) * 4);
    s += *(const f32x4*)(smem + 2 * 16384 + (qr * 64 + d0) * 4);
    s += *(const f32x4*)(smem + 3 * 16384 + (qr * 64 + d0) * 4);
    float l = ((float*)(smem + 0 * 16384 + 4096))[qr] + ((float*)(smem + 1 * 16384 + 4096))[qr] +
              ((float*)(smem + 2 * 16384 + 4096))[qr] + ((float*)(smem + 3 * 16384 + 4096))[qr];
    float inv = 1.0f / l;
    size_t idx = base + (size_t)(q0 + qr) * DHEAD + d0;
    f32x4 qv = *(const f32x4*)(qp32 + idx);
    f32x4 res = qv + s * inv;
    ushort4v hb;
#pragma unroll
    for (int j = 0; j < 4; ++j) hb[j] = f2bf(res[j]);
    *(ushort4v*)&head_lds[qr][d0] = hb;
  }
  __syncthreads();  // head ready for all waves

  // ---- fused out: out[q0+lg*4+r][w*256 + t*16 + l15] over K=64
  bf16x8 af0 = *(const bf16x8*)&head_lds[l15][lg * 8];
  bf16x8 af1 = *(const bf16x8*)&head_lds[l15][32 + lg * 8];
  size_t orow = ((size_t)b * S_LEN + q0 + lg * 4) * 1024;
  int c0 = w * 256;
#pragma unroll
  for (int t = 0; t < 16; ++t) {
    int col = c0 + t * 16 + l15;
    const unsigned short* bp = wosumT + (size_t)col * 64 + lg * 8;
    bf16x8 b0 = *(const bf16x8*)bp;
    bf16x8 b1 = *(const bf16x8*)(bp + 32);
    f32x4 acc = {};
    acc = mfma16(af0, b0, acc);
    acc = mfma16(af1, b1, acc);
    float bias = bo[col];
#pragma unroll
    for (int r = 0; r < 4; ++r) out[orow + (size_t)r * 1024 + col] = acc[r] + bias;
  }
}

extern "C" void kernel_launch(void* const* d_in, const int* in_sizes, int n_in,
                              void* d_out, int out_size, void* d_ws, size_t ws_size,
                              hipStream_t stream) {
  (void)in_sizes; (void)n_in; (void)out_size; (void)ws_size;
  const float* v = (const float*)d_in[0];
  const float* k = (const float*)d_in[1];
  const float* q = (const float*)d_in[2];
  const float* wi = (const float*)d_in[3];
  const float* Wo = (const float*)d_in[4];
  const float* bo = (const float*)d_in[5];
  float* out = (float*)d_out;
  char* ws = (char*)d_ws;

  float* qp32 = (float*)(ws + 0);                                // 2 MB
  unsigned short* qp_bf = (unsigned short*)(ws + (4u << 20));    // 1 MB
  unsigned short* kp_bf = (unsigned short*)(ws + (5u << 20));    // 1 MB
  unsigned short* vpT = (unsigned short*)(ws + (6u << 20));      // 1 MB tiled [b][32][64][64]
  unsigned short* wiT = (unsigned short*)(ws + (7u << 20));      // 128 KB
  unsigned short* wosumT = (unsigned short*)(ws + (7u << 20) + (512u << 10));  // 128 KB

  prep_kernel<<<512, 256, 0, stream>>>(wi, Wo, wiT, wosumT);
  proj_kernel<<<1536, 64, 0, stream>>>(q, k, v, wiT, qp32, qp_bf, kp_bf, vpT);
  attn_out_kernel<<<512, 256, 0, stream>>>(qp_bf, kp_bf, vpT, qp32, wosumT, bo, out);
}

// Round 10
// 57.211 us; speedup vs baseline: 1.8925x; 1.0022x over previous
//
#include <hip/hip_runtime.h>

typedef __bf16 bf16x8 __attribute__((ext_vector_type(8)));
typedef float f32x4 __attribute__((ext_vector_type(4)));
typedef unsigned short ushort8 __attribute__((ext_vector_type(8)));
typedef unsigned short ushort4v __attribute__((ext_vector_type(4)));

#define S_LEN 2048
#define DMODEL 1024
#define DHEAD 64
#define QK_SCALE 0.18033688f  /* (1/8) * log2(e) */

static __device__ __forceinline__ unsigned short f2bf(float x) {
  __bf16 h = (__bf16)x;
  return __builtin_bit_cast(unsigned short, h);
}

static __device__ __forceinline__ f32x4 mfma16(bf16x8 a, bf16x8 b, f32x4 c) {
  return __builtin_amdgcn_mfma_f32_16x16x32_bf16(a, b, c, 0, 0, 0);
}

#define GLOAD_LDS(SRC, DST)                                                            \
  __builtin_amdgcn_global_load_lds(                                                    \
      (const __attribute__((address_space(1))) void*)(SRC),                            \
      (__attribute__((address_space(3))) void*)(DST), 16, 0, 0)

// ---- fused prep: wiT [64][1024] bf16  +  wosumT [1024][64] bf16
__global__ void prep_kernel(const float* __restrict__ wi, const float* __restrict__ Wo,
                            unsigned short* __restrict__ wiT,
                            unsigned short* __restrict__ wosumT) {
  int i = blockIdx.x * 256 + threadIdx.x;  // 131072 total
  if (i < 65536) {
    int n = i >> 10, kk = i & 1023;
    wiT[i] = f2bf(wi[(size_t)kk * DHEAD + n]);
  } else {
    int idx = i - 65536;
    int j = idx & 1023, d = idx >> 10;
    float s = 0.f;
#pragma unroll
    for (int h = 0; h < 16; ++h) s += Wo[(size_t)(h * 64 + d) * 1024 + j];
    wosumT[(size_t)j * 64 + d] = f2bf(s);
  }
}

// ---- projections (r3 form, FROZEN: 96MB fp32 cold-read wall ~40us, six-shape
// invariant, proven by r6 cvt probe). Only change vs r9: V epilogue writes 32-kv
// tiled vpT [b][kvblk=64][dh=64][kvin=32] (4KB contiguous per tile) for attn's
// double-buffered 32-kv V staging.
__global__ __launch_bounds__(64) void proj_kernel(
    const float* __restrict__ q, const float* __restrict__ k, const float* __restrict__ v,
    const unsigned short* __restrict__ wiT,
    float* __restrict__ qp32, unsigned short* __restrict__ qp_bf,
    unsigned short* __restrict__ kp_bf, unsigned short* __restrict__ vpT) {
  int bx = blockIdx.x;       // 1536 blocks: 512 per tensor
  int ten = bx >> 9;         // 0:q 1:k 2:v
  int m0 = (bx & 511) << 4;  // 16-row strip
  const float* x = (ten == 0) ? q : ((ten == 1) ? k : v);
  int lane = threadIdx.x;
  int l15 = lane & 15, lg = lane >> 4;

  __shared__ __align__(16) char As[4 * 2048];
  __shared__ __align__(16) char Bs[4 * 4096];
  __shared__ __align__(16) unsigned short vt[16][72];

  const char* xb = (const char*)x;
  const char* wb = (const char*)wiT;

  const char* pA0 = xb + (size_t)(m0 + (lane >> 3)) * 4096 + ((((lane & 7) ^ (lane >> 3))) << 4);
  const char* pA1 = pA0 + 8 * 4096;
  const char* pB = wb + (size_t)(lane >> 2) * 2048 + ((((lane & 3) ^ ((lane >> 2) & 3))) << 4);

  auto ISSUE = [&](int st) {
    int buf = st & 3;
    char* ad = As + buf * 2048;
    char* bd = Bs + buf * 4096;
    GLOAD_LDS(pA0 + st * 128, ad);
    GLOAD_LDS(pA1 + st * 128, ad + 1024);
#pragma unroll
    for (int j = 0; j < 4; ++j) GLOAD_LDS(pB + j * 32768 + st * 64, bd + j * 1024);
  };

  f32x4 acc[4] = {};
  int swA = (l15 & 7) << 4;
  int swB = (l15 & 3) << 4;

  auto COMP = [&](int kt) {
    const char* Ab = As + (kt & 3) * 2048 + l15 * 128;
    f32x4 a0 = *(const f32x4*)(Ab + ((lg * 32) ^ swA));
    f32x4 a1 = *(const f32x4*)(Ab + ((lg * 32 + 16) ^ swA));
    bf16x8 af;
    af[0] = (__bf16)a0[0]; af[1] = (__bf16)a0[1]; af[2] = (__bf16)a0[2]; af[3] = (__bf16)a0[3];
    af[4] = (__bf16)a1[0]; af[5] = (__bf16)a1[1]; af[6] = (__bf16)a1[2]; af[7] = (__bf16)a1[3];
    const char* Bb = Bs + (kt & 3) * 4096 + ((lg * 16) ^ swB) + l15 * 64;
#pragma unroll
    for (int t = 0; t < 4; ++t) {
      bf16x8 bfr = *(const bf16x8*)(Bb + t * 1024);
      acc[t] = mfma16(af, bfr, acc[t]);
    }
  };

  ISSUE(0);
  ISSUE(1);
  ISSUE(2);
#pragma unroll 1
  for (int kt = 0; kt < 29; ++kt) {
    ISSUE(kt + 3);
    asm volatile("s_waitcnt vmcnt(18)" ::: "memory");
    __builtin_amdgcn_sched_barrier(0);
    COMP(kt);
    __builtin_amdgcn_sched_barrier(0);
  }
  asm volatile("s_waitcnt vmcnt(12)" ::: "memory");
  __builtin_amdgcn_sched_barrier(0);
  COMP(29);
  asm volatile("s_waitcnt vmcnt(6)" ::: "memory");
  __builtin_amdgcn_sched_barrier(0);
  COMP(30);
  asm volatile("s_waitcnt vmcnt(0)" ::: "memory");
  __builtin_amdgcn_sched_barrier(0);
  COMP(31);

  if (ten == 2) {
#pragma unroll
    for (int t = 0; t < 4; ++t)
#pragma unroll
      for (int r = 0; r < 4; ++r)
        vt[lg * 4 + r][t * 16 + l15] = f2bf(acc[t][r]);
    __syncthreads();  // single-wave block: cheap
    int bq = m0 >> 11, kvb = m0 & 2047;
    // 32-kv tiled vpT: [b][kvb>>5][dh=lane][kvin 32], tile = 2048 shorts (4KB)
    unsigned short* dst = vpT + (size_t)bq * 131072 + (size_t)(kvb >> 5) * 2048 +
                          (size_t)lane * 32 + (kvb & 31);
    ushort8 o0, o1;
#pragma unroll
    for (int j = 0; j < 8; ++j) {
      o0[j] = vt[j][lane];
      o1[j] = vt[8 + j][lane];
    }
    *(ushort8*)dst = o0;
    *(ushort8*)(dst + 8) = o1;
  } else {
#pragma unroll
    for (int t = 0; t < 4; ++t) {
      int gc = t * 16 + l15;
#pragma unroll
      for (int r = 0; r < 4; ++r) {
        size_t idx = (size_t)(m0 + lg * 4 + r) * DHEAD + gc;
        float val = acc[t][r];
        if (ten == 0) {
          qp32[idx] = val;
          qp_bf[idx] = f2bf(val * QK_SCALE);
        } else {
          kp_bf[idx] = f2bf(val);
        }
      }
    }
  }
}

// ---- flash attention + fused out, depth-2 double-buffered 32-kv pipeline.
// r9 post-mortem: staging worked (43.8 -> ~13us) but was prefetch-depth-1: K(it+1)
// issued only after QK(it), exposing part of the L2->LDS round-trip at 2 waves/SIMD.
// r10: 32-kv stages, double-buffered K and V (4 x 4KB/wave, same 64KB footprint,
// still 2 blocks/CU): while computing it, it+1 is landed/in-flight and it+2 issuing.
// Counted vmcnt(12) steady state; drain 8/4/0 only at tail. Wave-local => no in-loop
// barriers. part/lsum/head alias tiles post-loop.
__global__ __launch_bounds__(256, 2) void attn_out_kernel(
    const unsigned short* __restrict__ qp_bf, const unsigned short* __restrict__ kp_bf,
    const unsigned short* __restrict__ vpT, const float* __restrict__ qp32,
    const unsigned short* __restrict__ wosumT, const float* __restrict__ bo,
    float* __restrict__ out) {
  int bx = blockIdx.x;
  int b = bx >> 7;
  int q0 = (bx & 127) << 4;
  int tid = threadIdx.x, lane = tid & 63, w = tid >> 6;
  int l15 = lane & 15, lg = lane >> 4;
  int r8 = lane >> 3, c8 = lane & 7;

  __shared__ __align__(16) char smem[70656];
  char* Kt0 = smem + w * 16384;  // [32 kv][128B], row-XOR swz
  char* Kt1 = Kt0 + 4096;
  char* Vt0 = Kt0 + 8192;        // [64 dh][64B], row-XOR swz
  char* Vt1 = Kt0 + 12288;
  unsigned short* P_w = (unsigned short*)(smem + 65536 + w * 1280);  // [16][40]
  float* part_w = (float*)Kt0;                                        // alias post-loop
  float* lsum_w = (float*)Vt0;
  unsigned short(*head_lds)[72] = (unsigned short(*)[72])(smem + 65536);

  size_t base = (size_t)b * (S_LEN * DHEAD);
  const unsigned short* qrow_p = qp_bf + base + (size_t)(q0 + l15) * DHEAD + lg * 8;
  bf16x8 qf0 = *(const bf16x8*)qrow_p;
  bf16x8 qf1 = *(const bf16x8*)(qrow_p + 32);

  // pre-swizzled DMA sources (dest linear: lane -> +lane*16 within each 1KB)
  const char* pK = (const char*)(kp_bf + base) + r8 * 128 + ((c8 ^ r8) << 4) +
                   (size_t)w * 512 * 128;
  const char* pV = (const char*)vpT + (size_t)b * 262144 + (lane >> 2) * 64 +
                   ((((lane & 3) ^ ((lane >> 2) & 3))) << 4) + (size_t)w * 16 * 4096;

  auto KISSUE = [&](int it2, char* dstK) {
    const char* s = pK + (size_t)it2 * 4096;
#pragma unroll
    for (int j = 0; j < 4; ++j) GLOAD_LDS(s + j * 1024, dstK + j * 1024);
  };
  auto VISSUE = [&](int it2, char* dstV) {
    const char* s = pV + (size_t)it2 * 4096;
#pragma unroll
    for (int j = 0; j < 4; ++j) GLOAD_LDS(s + j * 1024, dstV + j * 1024);
  };

  f32x4 oacc[4] = {};
  float lsum_p = 0.f;
  int swzK = (l15 & 7) << 4;
  int swzV = (l15 & 3);

  KISSUE(0, Kt0);
  VISSUE(0, Vt0);
  KISSUE(1, Kt1);
  VISSUE(1, Vt1);
#pragma unroll
  for (int it = 0; it < 16; ++it) {
    char* Kc = (it & 1) ? Kt1 : Kt0;
    char* Vc = (it & 1) ? Vt1 : Vt0;
    // K(it) landed
    if (it < 15) {
      asm volatile("s_waitcnt vmcnt(12)" ::: "memory");
    } else {
      asm volatile("s_waitcnt vmcnt(4)" ::: "memory");
    }
    __builtin_amdgcn_sched_barrier(0);
    f32x4 sc[2];
#pragma unroll
    for (int sub = 0; sub < 2; ++sub) {
      const char* kr = Kc + (sub * 16 + l15) * 128;
      bf16x8 kf0 = *(const bf16x8*)(kr + ((lg * 16) ^ swzK));
      bf16x8 kf1 = *(const bf16x8*)(kr + ((64 + lg * 16) ^ swzK));
      f32x4 z = {};
      z = mfma16(kf0, qf0, z);
      sc[sub] = mfma16(kf1, qf1, z);
    }
    asm volatile("s_waitcnt lgkmcnt(0)" ::: "memory");  // kf consumed; Kc reusable
    __builtin_amdgcn_sched_barrier(0);
    if (it < 14) KISSUE(it + 2, Kc);
    // softmax while V(it) / K(it+2) fly
#pragma unroll
    for (int sub = 0; sub < 2; ++sub) {
      ushort4v pw;
#pragma unroll
      for (int r = 0; r < 4; ++r) {
        float p = exp2f(sc[sub][r]);
        lsum_p += p;
        pw[r] = f2bf(p);
      }
      *(ushort4v*)(P_w + l15 * 40 + sub * 16 + lg * 4) = pw;
    }
    // V(it) landed
    if (it < 14) {
      asm volatile("s_waitcnt vmcnt(12)" ::: "memory");
    } else if (it == 14) {
      asm volatile("s_waitcnt vmcnt(8)" ::: "memory");
    } else {
      asm volatile("s_waitcnt vmcnt(0)" ::: "memory");
    }
    __builtin_amdgcn_sched_barrier(0);
    bf16x8 pf = *(const bf16x8*)(P_w + l15 * 40 + lg * 8);
#pragma unroll
    for (int t = 0; t < 4; ++t) {
      int vrow = t * 16 + l15;
      const char* vr = Vc + vrow * 64 + (((lg ^ swzV)) << 4);
      bf16x8 vf = *(const bf16x8*)vr;
      oacc[t] = mfma16(pf, vf, oacc[t]);
    }
    asm volatile("s_waitcnt lgkmcnt(0)" ::: "memory");  // vf consumed; Vc reusable
    __builtin_amdgcn_sched_barrier(0);
    if (it < 14) VISSUE(it + 2, Vc);
  }

  // finish denom: reduce across the 4 lg groups (same l15 = same q)
  lsum_p += __shfl_xor(lsum_p, 16);
  lsum_p += __shfl_xor(lsum_p, 32);

  // per-wave partials into own (now free) tile regions
#pragma unroll
  for (int t = 0; t < 4; ++t)
#pragma unroll
    for (int r = 0; r < 4; ++r)
      part_w[(lg * 4 + r) * 64 + t * 16 + l15] = oacc[t][r];
  if (lane < 16) lsum_w[l15] = lsum_p;
  __syncthreads();  // cross-wave combine barrier

  {
    int qr = tid >> 4, d0 = (tid & 15) << 2;
    f32x4 s = *(const f32x4*)(smem + 0 * 16384 + (qr * 64 + d0) * 4);
    s += *(const f32x4*)(smem + 1 * 16384 + (qr * 64 + d0) * 4);
    s += *(const f32x4*)(smem + 2 * 16384 + (qr * 64 + d0) * 4);
    s += *(const f32x4*)(smem + 3 * 16384 + (qr * 64 + d0) * 4);
    float l = ((float*)(smem + 0 * 16384 + 8192))[qr] + ((float*)(smem + 1 * 16384 + 8192))[qr] +
              ((float*)(smem + 2 * 16384 + 8192))[qr] + ((float*)(smem + 3 * 16384 + 8192))[qr];
    float inv = 1.0f / l;
    size_t idx = base + (size_t)(q0 + qr) * DHEAD + d0;
    f32x4 qv = *(const f32x4*)(qp32 + idx);
    f32x4 res = qv + s * inv;
    ushort4v hb;
#pragma unroll
    for (int j = 0; j < 4; ++j) hb[j] = f2bf(res[j]);
    *(ushort4v*)&head_lds[qr][d0] = hb;
  }
  __syncthreads();  // head ready for all waves

  // ---- fused out: out[q0+lg*4+r][w*256 + t*16 + l15] over K=64
  bf16x8 af0 = *(const bf16x8*)&head_lds[l15][lg * 8];
  bf16x8 af1 = *(const bf16x8*)&head_lds[l15][32 + lg * 8];
  size_t orow = ((size_t)b * S_LEN + q0 + lg * 4) * 1024;
  int c0 = w * 256;
#pragma unroll
  for (int t = 0; t < 16; ++t) {
    int col = c0 + t * 16 + l15;
    const unsigned short* bp = wosumT + (size_t)col * 64 + lg * 8;
    bf16x8 b0 = *(const bf16x8*)bp;
    bf16x8 b1 = *(const bf16x8*)(bp + 32);
    f32x4 acc = {};
    acc = mfma16(af0, b0, acc);
    acc = mfma16(af1, b1, acc);
    float bias = bo[col];
#pragma unroll
    for (int r = 0; r < 4; ++r) out[orow + (size_t)r * 1024 + col] = acc[r] + bias;
  }
}

extern "C" void kernel_launch(void* const* d_in, const int* in_sizes, int n_in,
                              void* d_out, int out_size, void* d_ws, size_t ws_size,
                              hipStream_t stream) {
  (void)in_sizes; (void)n_in; (void)out_size; (void)ws_size;
  const float* v = (const float*)d_in[0];
  const float* k = (const float*)d_in[1];
  const float* q = (const float*)d_in[2];
  const float* wi = (const float*)d_in[3];
  const float* Wo = (const float*)d_in[4];
  const float* bo = (const float*)d_in[5];
  float* out = (float*)d_out;
  char* ws = (char*)d_ws;

  float* qp32 = (float*)(ws + 0);                                // 2 MB
  unsigned short* qp_bf = (unsigned short*)(ws + (4u << 20));    // 1 MB
  unsigned short* kp_bf = (unsigned short*)(ws + (5u << 20));    // 1 MB
  unsigned short* vpT = (unsigned short*)(ws + (6u << 20));      // 1 MB tiled [b][64][64][32]
  unsigned short* wiT = (unsigned short*)(ws + (7u << 20));      // 128 KB
  unsigned short* wosumT = (unsigned short*)(ws + (7u << 20) + (512u << 10));  // 128 KB

  prep_kernel<<<512, 256, 0, stream>>>(wi, Wo, wiT, wosumT);
  proj_kernel<<<1536, 64, 0, stream>>>(q, k, v, wiT, qp32, qp_bf, kp_bf, vpT);
  attn_out_kernel<<<512, 256, 0, stream>>>(qp_bf, kp_bf, vpT, qp32, wosumT, bo, out);
}